// Round 5
// baseline (312.508 us; speedup 1.0000x reference)
//
#include <hip/hip_runtime.h>

typedef __bf16 bf16_t;
typedef __bf16 bf16x8 __attribute__((ext_vector_type(8)));
typedef float  f32x4  __attribute__((ext_vector_type(4)));

constexpr int B_   = 64;
constexpr int EMB_ = 256;
constexpr int H_   = 256;
constexpr int NP_  = 512;
constexpr int NC_  = 144;
constexpr int CL_  = 684;
constexpr int CH_  = 342;
constexpr int LL_  = 256;
constexpr int LH_  = 576;
constexpr int OF_  = 256;
constexpr int CTX_ = 1026;
constexpr int LDC_ = 1032;  // ctx row stride
constexpr int CPL_ = 704;   // CL padded to 11*64
constexpr int CPH_ = 384;   // CH padded to 6*64

// ---- workspace layout (float offsets) ----
constexpr size_t OFF_EMB  = 0;        // [64][256]
constexpr size_t OFF_PRED = 16384;    // [64][256]
constexpr size_t OFF_PS1  = 32768;    // [4][64][1536]  gi1|gh1
constexpr size_t OFF_PSUP = 425984;   // [4][64][1792]  upL|upH|gh2
constexpr size_t OFF_PS2  = 884736;   // [8][64][1024]  gi2|wc
constexpr size_t OFF_OFL  = 1409024;  // [256][256]
constexpr size_t OFF_OFH  = 1474560;  // [576][256]
constexpr size_t OFF_UFL  = 1622016;  // [512][256]
constexpr size_t OFF_UFH  = 1753088;  // [512][576]
constexpr size_t OFF_EL   = 2048000;  // [64][256]
constexpr size_t OFF_EH   = 2064384;  // [64][576]
constexpr size_t OFF_CTX  = 2101248;  // [64][1032]
constexpr size_t OFF_UAL  = 2167296;  // bf16[512][704]
constexpr size_t OFF_UAH  = 2347520;  // bf16[512][384]

__device__ __forceinline__ float sigm(float x) { return 1.f / (1.f + expf(-x)); }
__device__ __forceinline__ float ftanh(float x) {
  float e = __expf(2.f * x);
  return 1.f - 2.f * __builtin_amdgcn_rcpf(e + 1.f);
}

// ---------------- merged front: U_a->bf16 | embed | out_f ----------------
__global__ __launch_bounds__(256) void k_front(
    const float* __restrict__ UaL, const float* __restrict__ UaH,
    bf16_t* __restrict__ dL, bf16_t* __restrict__ dH,
    const int* __restrict__ x, const float* __restrict__ embedding,
    float* __restrict__ emb,
    const float* __restrict__ aL, const float* __restrict__ aH,
    const float* __restrict__ fwL, const float* __restrict__ fbL,
    const float* __restrict__ fwH, const float* __restrict__ fbH,
    float* __restrict__ ofL, float* __restrict__ ofH) {
  __shared__ float al[LH_];
  __shared__ int nz;
  int bid = blockIdx.x, t = threadIdx.x;
  if (bid < 2176) {  // prep
    int idx = bid * 256 + t;
    if (idx < NP_ * CPL_) {
      int r = idx / CPL_, k = idx - r * CPL_;
      float v = (k < CL_) ? UaL[r * CL_ + k] : 0.f;
      dL[idx] = (bf16_t)v;
    } else {
      int i2 = idx - NP_ * CPL_;
      int r = i2 / CPH_, k = i2 - r * CPH_;
      float v = (k < CH_) ? UaH[r * CH_ + k] : 0.f;
      dH[i2] = (bf16_t)v;
    }
    return;
  }
  if (bid < 2240) {  // embed
    int b = bid - 2176;
    emb[b * EMB_ + t] = embedding[(size_t)x[b] * EMB_ + t];
    return;
  }
  // out_f (zero-alpha fast path)
  int bo = bid - 2240;
  bool low = bo < 256;
  const float* alpha = low ? aL : aH;
  int L = low ? LL_ : LH_;
  const float* fw = low ? fwL : fwH;
  const float* fb = low ? fbL : fbH;
  float* of = low ? ofL : ofH;
  int row = (low ? bo : bo - 256) * 256 + t;
  if (t == 0) nz = 0;
  __syncthreads();
  int any = 0;
  for (int l = t; l < L; l += 256) { float v = alpha[l]; al[l] = v; any |= (v != 0.f); }
  if (any) atomicOr(&nz, 1);
  __syncthreads();
  float s = fb[row];
  if (nz) {
    const float4* w4 = (const float4*)(fw + (size_t)row * L);
    for (int k = 0; k < L / 4; ++k) {
      float4 a4 = w4[k];
      s += al[4*k]*a4.x + al[4*k+1]*a4.y + al[4*k+2]*a4.z + al[4*k+3]*a4.w;
    }
  }
  of[row] = s;
}

// ---------------- generic split-K batched matvec ----------------
__global__ __launch_bounds__(256) void k_mv(
    const float* __restrict__ W0, const float* __restrict__ W1, const float* __restrict__ W2,
    const float* __restrict__ X0, const float* __restrict__ X1, const float* __restrict__ X2,
    int n0, int n1, int K, int ldx, int SK, int Nt,
    float* __restrict__ O) {
  int j0 = blockIdx.x * 32;
  int s  = blockIdx.y;
  const float* W; const float* X; int jr;
  if (j0 < n0)           { W = W0; X = X0; jr = j0; }
  else if (j0 < n0 + n1) { W = W1; X = X1; jr = j0 - n0; }
  else                   { W = W2; X = X2; jr = j0 - n0 - n1; }
  int NCh = (K + 63) >> 6;
  int c0 = (s * NCh) / SK, c1 = ((s + 1) * NCh) / SK;
  __shared__ float sX[64][68];
  __shared__ float sW[32][68];
  int t = threadIdx.x;
  int jg = t >> 5, bg = t & 31;
  float acc[4][2];
  #pragma unroll
  for (int r = 0; r < 4; ++r) { acc[r][0] = 0.f; acc[r][1] = 0.f; }
  for (int c = c0; c < c1; ++c) {
    int kb = c << 6;
    #pragma unroll
    for (int i = 0; i < 16; ++i) {
      int idx = t + (i << 8);
      int row = idx >> 6, col = idx & 63, k = kb + col;
      sX[row][col] = (k < K) ? X[(size_t)row * ldx + k] : 0.f;
    }
    #pragma unroll
    for (int i = 0; i < 8; ++i) {
      int idx = t + (i << 8);
      int row = idx >> 6, col = idx & 63, k = kb + col;
      sW[row][col] = (k < K) ? W[(size_t)(jr + row) * K + k] : 0.f;
    }
    __syncthreads();
    #pragma unroll
    for (int kg = 0; kg < 16; ++kg) {
      float4 xa = *(const float4*)&sX[bg][kg * 4];
      float4 xb = *(const float4*)&sX[bg + 32][kg * 4];
      #pragma unroll
      for (int r = 0; r < 4; ++r) {
        float4 w4 = *(const float4*)&sW[jg * 4 + r][kg * 4];
        acc[r][0] += w4.x*xa.x + w4.y*xa.y + w4.z*xa.z + w4.w*xa.w;
        acc[r][1] += w4.x*xb.x + w4.y*xb.y + w4.z*xb.z + w4.w*xb.w;
      }
    }
    __syncthreads();
  }
  #pragma unroll
  for (int r = 0; r < 4; ++r) {
    int j = j0 + jg * 4 + r;
    O[((size_t)(s * 64) + bg) * Nt + j]      = acc[r][0];
    O[((size_t)(s * 64) + bg + 32) * Nt + j] = acc[r][1];
  }
}

// ---------------- GRU1 activation (combine 4 K-slices) ----------------
__global__ __launch_bounds__(256) void k_act1(const float* __restrict__ PS1,
                                              const float* __restrict__ hidden,
                                              float* __restrict__ pred) {
  int b = blockIdx.x, t = threadIdx.x;
  float gr = 0, gz = 0, gn = 0, hr = 0, hz = 0, hn = 0;
  #pragma unroll
  for (int s = 0; s < 4; ++s) {
    const float* row = PS1 + ((size_t)(s * 64) + b) * 1536;
    gr += row[t]; gz += row[256 + t]; gn += row[512 + t];
    hr += row[768 + t]; hz += row[1024 + t]; hn += row[1280 + t];
  }
  float hv = hidden[b * H_ + t];
  float r = sigm(gr + hr);
  float z = sigm(gz + hz);
  float n = tanhf(gn + r * hn);
  pred[b * H_ + t] = (1.f - z) * n + z * hv;
}

// ---------------- u_f[p,l] = sum_o U_f[p,o] * out_f[l,o] ----------------
__global__ __launch_bounds__(256) void k_uf(
    const float* __restrict__ UfL, const float* __restrict__ UfH,
    const float* __restrict__ ofL, const float* __restrict__ ofH,
    float* __restrict__ ufL, float* __restrict__ ufH) {
  int bid = blockIdx.x, t = threadIdx.x;
  bool low = bid < 64;
  const float* Uf = low ? UfL : UfH;
  const float* of = low ? ofL : ofH;
  float* uf = low ? ufL : ufH;
  int L = low ? LL_ : LH_;
  int p0 = (low ? bid : bid - 64) * 8;
  __shared__ float ufs[8][OF_];
  for (int i = t; i < 8 * OF_; i += 256) ufs[i >> 8][i & 255] = Uf[(size_t)(p0 + (i >> 8)) * OF_ + (i & 255)];
  __syncthreads();
  for (int l = t; l < L; l += 256) {
    const float4* o4 = (const float4*)(of + (size_t)l * OF_);
    float acc[8] = {0,0,0,0,0,0,0,0};
    for (int k = 0; k < OF_ / 4; ++k) {
      float4 v = o4[k];
      #pragma unroll
      for (int i = 0; i < 8; ++i)
        acc[i] += v.x*ufs[i][4*k] + v.y*ufs[i][4*k+1] + v.z*ufs[i][4*k+2] + v.w*ufs[i][4*k+3];
    }
    #pragma unroll
    for (int i = 0; i < 8; ++i) uf[(size_t)(p0 + i) * L + l] = acc[i];
  }
}

// ---------------- u_a GEMM: A-frags direct from L2, B-only LDS pipeline ----------------
// grid (13, 64): bx<4 -> low l-tile bx; bx>=4 -> high l-tile bx-4
__global__ __launch_bounds__(512, 4) void k_ua(
    const bf16_t* __restrict__ uaL, const bf16_t* __restrict__ uaH,
    const float* __restrict__ lowres, const float* __restrict__ highres,
    const float* __restrict__ psup,
    const float* __restrict__ ufL, const float* __restrict__ ufH,
    const float* __restrict__ nuL, const float* __restrict__ nuH,
    float* __restrict__ eL, float* __restrict__ eH) {
  int bx = blockIdx.x, b = blockIdx.y;
  bool lo = bx < 4;
  int lt = lo ? bx : bx - 4;
  int C  = lo ? CL_ : CH_;
  int CP = lo ? CPL_ : CPH_;
  int L  = lo ? LL_ : LH_;
  int upoff = lo ? 0 : 512;
  const bf16_t* Uab = lo ? uaL : uaH;
  const float* a    = lo ? lowres : highres;
  const float* uf   = lo ? ufL : ufH;
  const float* nu   = lo ? nuL : nuH;
  float* e_out      = lo ? eL : eH;
  int KC = CP >> 6;
  int l0 = lt * 64;
  int t = threadIdx.x;
  int w = t >> 6, lane = t & 63, g = lane >> 4, ln = lane & 15;

  __shared__ bf16_t Bsm[64 * 64];   // [l][k-slot], slot ^= (l&7): conflict-free
  __shared__ float ered[8][64];

  f32x4 acc[4][4];
  #pragma unroll
  for (int i = 0; i < 4; ++i)
    #pragma unroll
    for (int j = 0; j < 4; ++j) acc[i][j] = (f32x4){0.f, 0.f, 0.f, 0.f};

  const float* abase = a + ((size_t)b * C) * L + l0;
  int o = t >> 6, lcol = t & 63;                       // B staging coords
  const bf16_t* Abase = Uab + (size_t)(w * 64 + ln) * CP + g * 8;  // + ps*16*CP + kc*64 + ks*32

  float bpre[8];
  bf16x8 af[2][4];

  // ---- prologue: chunk 0 ----
  {
    int cb = o * 8;
    #pragma unroll
    for (int j = 0; j < 8; ++j) {
      int c = cb + j;
      bpre[j] = (c < C) ? abase[(size_t)c * L + lcol] : 0.f;
    }
    #pragma unroll
    for (int ks = 0; ks < 2; ++ks)
      #pragma unroll
      for (int ps = 0; ps < 4; ++ps)
        af[ks][ps] = *(const bf16x8*)(Abase + (size_t)ps * 16 * CP + ks * 32);
    bf16x8 bv;
    #pragma unroll
    for (int j = 0; j < 8; ++j) bv[j] = (bf16_t)bpre[j];
    *(bf16x8*)&Bsm[lcol * 64 + ((o ^ (lcol & 7)) << 3)] = bv;
  }

  for (int kc = 0; kc < KC; ++kc) {
    __syncthreads();                       // B(kc) visible
    bool more = (kc + 1 < KC);
    if (more) {                            // prefetch B(kc+1) into regs
      int cb = (kc + 1) * 64 + o * 8;
      #pragma unroll
      for (int j = 0; j < 8; ++j) {
        int c = cb + j;
        bpre[j] = (c < C) ? abase[(size_t)c * L + lcol] : 0.f;
      }
    }
    #pragma unroll
    for (int ks = 0; ks < 2; ++ks) {
      bf16x8 bfv[4];
      #pragma unroll
      for (int ts = 0; ts < 4; ++ts) {
        int lrow = ts * 16 + ln;
        int slot = ks * 4 + g;
        bfv[ts] = *(bf16x8*)&Bsm[lrow * 64 + (((slot ^ (lrow & 7))) << 3)];
      }
      #pragma unroll
      for (int ts = 0; ts < 4; ++ts)
        #pragma unroll
        for (int ps = 0; ps < 4; ++ps)
          acc[ps][ts] = __builtin_amdgcn_mfma_f32_16x16x32_bf16(af[ks][ps], bfv[ts], acc[ps][ts], 0, 0, 0);
    }
    if (more) {                            // prefetch A-frags(kc+1) after last use
      #pragma unroll
      for (int ks = 0; ks < 2; ++ks)
        #pragma unroll
        for (int ps = 0; ps < 4; ++ps)
          af[ks][ps] = *(const bf16x8*)(Abase + (size_t)ps * 16 * CP + (kc + 1) * 64 + ks * 32);
    }
    __syncthreads();                       // B(kc) reads done
    if (more) {                            // write B(kc+1)
      bf16x8 bv;
      #pragma unroll
      for (int j = 0; j < 8; ++j) bv[j] = (bf16_t)bpre[j];
      *(bf16x8*)&Bsm[lcol * 64 + ((o ^ (lcol & 7)) << 3)] = bv;
    }
  }

  // epilogue: e_part = sum_p nu[p] * tanh(acc + up[b,p] + uf[p,l])
  float ep[4] = {0.f, 0.f, 0.f, 0.f};
  #pragma unroll
  for (int ps = 0; ps < 4; ++ps) {
    int pbase = w * 64 + ps * 16 + 4 * g;
    float upv[4], nuv[4];
    #pragma unroll
    for (int r = 0; r < 4; ++r) {
      float u = 0.f;
      #pragma unroll
      for (int s = 0; s < 4; ++s)
        u += psup[((size_t)(s * 64) + b) * 1792 + upoff + pbase + r];
      upv[r] = u; nuv[r] = nu[pbase + r];
    }
    #pragma unroll
    for (int ts = 0; ts < 4; ++ts) {
      int l = l0 + ts * 16 + ln;
      #pragma unroll
      for (int r = 0; r < 4; ++r) {
        float v = acc[ps][ts][r] + upv[r] + uf[(size_t)(pbase + r) * L + l];
        ep[ts] += nuv[r] * ftanh(v);
      }
    }
  }
  #pragma unroll
  for (int ts = 0; ts < 4; ++ts) {
    float v = ep[ts];
    v += __shfl_xor(v, 16, 64);
    v += __shfl_xor(v, 32, 64);
    if (lane < 16) ered[w][ts * 16 + ln] = v;
  }
  __syncthreads();
  if (t < 64) {
    float s = 0.f;
    #pragma unroll
    for (int ww = 0; ww < 8; ++ww) s += ered[ww][t];
    e_out[b * L + l0 + t] = s;
  }
}

// ---------------- fused softmax(e) + ctx tile  (grid 17 x 64) ----------------
__global__ __launch_bounds__(256) void k_ctx(
    const float* __restrict__ eL, const float* __restrict__ eH,
    const float* __restrict__ lowres, const float* __restrict__ highres,
    float* __restrict__ ctx) {
  int tile = blockIdx.x, b = blockIdx.y, t = threadIdx.x;
  bool low = tile < 11;
  int C = low ? CL_ : CH_;
  int L = low ? LL_ : LH_;
  int c0 = (low ? tile : tile - 11) * 64;
  const float* e = low ? eL + b * LL_ : eH + b * LH_;
  const float* a = (low ? lowres : highres) + ((size_t)b * C) * L;
  float* co = ctx + (size_t)b * LDC_ + (low ? 0 : CL_) + c0;
  int rows = min(64, C - c0);
  __shared__ float als[LH_];
  __shared__ float red4[4];
  __shared__ float red[64][4];
  int wid = t >> 6, lane = t & 63;
  // softmax (recomputed per tile; trivial VALU)
  float m = -3.4e38f;
  for (int l = t; l < L; l += 256) m = fmaxf(m, e[l]);
  #pragma unroll
  for (int s = 1; s < 64; s <<= 1) m = fmaxf(m, __shfl_xor(m, s, 64));
  if (lane == 0) red4[wid] = m;
  __syncthreads();
  m = fmaxf(fmaxf(red4[0], red4[1]), fmaxf(red4[2], red4[3]));
  __syncthreads();
  float sum = 0.f;
  for (int l = t; l < L; l += 256) { float v = __expf(e[l] - m); als[l] = v; sum += v; }
  #pragma unroll
  for (int s = 1; s < 64; s <<= 1) sum += __shfl_xor(sum, s, 64);
  if (lane == 0) red4[wid] = sum;
  __syncthreads();
  float inv = 1.f / (red4[0] + red4[1] + red4[2] + red4[3]);
  for (int l = t; l < L; l += 256) als[l] *= inv;
  __syncthreads();
  // ctx
  int r = t >> 2, q = t & 3;
  int Lq = L >> 2;
  float s = 0.f;
  if (r < rows) {
    const float4* a4 = (const float4*)(a + (size_t)(c0 + r) * L + q * Lq);
    const float* alq = als + q * Lq;
    for (int k = 0; k < (Lq >> 2); ++k) {
      float4 v = a4[k];
      s += alq[4*k]*v.x + alq[4*k+1]*v.y + alq[4*k+2]*v.z + alq[4*k+3]*v.w;
    }
  }
  red[r][q] = s;
  __syncthreads();
  if (q == 0 && r < rows)
    co[r] = red[r][0] + red[r][1] + red[r][2] + red[r][3];
}

// ---------------- GRU2 act + w_s + sv + out projection ----------------
__global__ __launch_bounds__(256) void k_final(
    const float* __restrict__ PS2, const float* __restrict__ PSUP,
    const float* __restrict__ pred, const float* __restrict__ emb,
    const float* __restrict__ Ws, const float* __restrict__ Wo,
    const float* __restrict__ b_ih, const float* __restrict__ b_hh,
    float* __restrict__ out) {
  int b = blockIdx.x, t = threadIdx.x;
  __shared__ float nh[H_], sv[EMB_];
  float gr = b_ih[t], gz = b_ih[256 + t], gn = b_ih[512 + t];
  float wc_t = 0.f;
  #pragma unroll
  for (int s = 0; s < 8; ++s) {
    const float* row = PS2 + ((size_t)(s * 64) + b) * 1024;
    gr += row[t]; gz += row[256 + t]; gn += row[512 + t];
    wc_t += row[768 + t];
  }
  float hr = b_hh[t], hz = b_hh[256 + t], hn = b_hh[512 + t];
  #pragma unroll
  for (int s = 0; s < 4; ++s) {
    const float* row = PSUP + ((size_t)(s * 64) + b) * 1792;
    hr += row[1024 + t]; hz += row[1280 + t]; hn += row[1536 + t];
  }
  float hv = pred[b * H_ + t];
  float r = sigm(gr + hr);
  float z = sigm(gz + hz);
  float n = tanhf(gn + r * hn);
  float h = (1.f - z) * n + z * hv;
  nh[t] = h;
  out[NC_ * B_ + b * H_ + t] = h;
  __syncthreads();
  {
    const float4* ws4 = (const float4*)(Ws + (size_t)t * H_);
    float s1 = 0.f;
    for (int k = 0; k < H_ / 4; ++k) {
      float4 v = ws4[k];
      s1 += nh[4*k]*v.x + nh[4*k+1]*v.y + nh[4*k+2]*v.z + nh[4*k+3]*v.w;
    }
    sv[t] = emb[b * EMB_ + t] + s1 + wc_t;
  }
  __syncthreads();
  if (t < NC_) {
    const float4* wo4 = (const float4*)(Wo + (size_t)t * EMB_);
    float s = 0.f;
    for (int k = 0; k < EMB_ / 4; ++k) {
      float4 v = wo4[k];
      s += sv[4*k]*v.x + sv[4*k+1]*v.y + sv[4*k+2]*v.z + sv[4*k+3]*v.w;
    }
    out[b * NC_ + t] = s;
  }
}

extern "C" void kernel_launch(void* const* d_in, const int* in_sizes, int n_in,
                              void* d_out, int out_size, void* d_ws, size_t ws_size,
                              hipStream_t stream) {
  (void)in_sizes; (void)n_in; (void)out_size; (void)ws_size;
  const int*   x       = (const int*)  d_in[0];
  const float* hidden  = (const float*)d_in[1];
  const float* lowres  = (const float*)d_in[2];
  const float* highres = (const float*)d_in[3];
  const float* aLow    = (const float*)d_in[4];
  const float* aHigh   = (const float*)d_in[5];
  const float* embd    = (const float*)d_in[6];
  const float* g1wih   = (const float*)d_in[7];
  const float* g1whh   = (const float*)d_in[8];
  const float* g1bih   = (const float*)d_in[9];
  const float* g1bhh   = (const float*)d_in[10];
  const float* g2wih   = (const float*)d_in[11];
  const float* g2whh   = (const float*)d_in[12];
  const float* g2bih   = (const float*)d_in[13];
  const float* g2bhh   = (const float*)d_in[14];
  const float* fwL     = (const float*)d_in[15];
  const float* fbL     = (const float*)d_in[16];
  const float* UpL     = (const float*)d_in[17];
  const float* UaL     = (const float*)d_in[18];
  const float* UfL     = (const float*)d_in[19];
  const float* nuL     = (const float*)d_in[20];
  const float* fwH     = (const float*)d_in[21];
  const float* fbH     = (const float*)d_in[22];
  const float* UpH     = (const float*)d_in[23];
  const float* UaH     = (const float*)d_in[24];
  const float* UfH     = (const float*)d_in[25];
  const float* nuH     = (const float*)d_in[26];
  const float* Wo      = (const float*)d_in[27];
  const float* Ws      = (const float*)d_in[28];
  const float* Wc      = (const float*)d_in[29];

  float* ws  = (float*)d_ws;
  float* out = (float*)d_out;
  float* w_emb  = ws + OFF_EMB;
  float* w_pred = ws + OFF_PRED;
  float* w_ps1  = ws + OFF_PS1;
  float* w_psup = ws + OFF_PSUP;
  float* w_ps2  = ws + OFF_PS2;
  float* w_ofL  = ws + OFF_OFL;
  float* w_ofH  = ws + OFF_OFH;
  float* w_ufL  = ws + OFF_UFL;
  float* w_ufH  = ws + OFF_UFH;
  float* w_eL   = ws + OFF_EL;
  float* w_eH   = ws + OFF_EH;
  float* w_ctx  = ws + OFF_CTX;
  bf16_t* uaLb  = (bf16_t*)(ws + OFF_UAL);
  bf16_t* uaHb  = (bf16_t*)(ws + OFF_UAH);

  k_front<<<3072, 256, 0, stream>>>(UaL, UaH, uaLb, uaHb, x, embd, w_emb,
                                    aLow, aHigh, fwL, fbL, fwH, fbH, w_ofL, w_ofH);
  k_uf<<<128, 256, 0, stream>>>(UfL, UfH, w_ofL, w_ofH, w_ufL, w_ufH);

  k_mv<<<dim3(48, 4), 256, 0, stream>>>(g1wih, g1whh, nullptr,
                                        w_emb, hidden, nullptr,
                                        768, 768, 256, 256, 4, 1536, w_ps1);
  k_act1<<<B_, 256, 0, stream>>>(w_ps1, hidden, w_pred);
  k_mv<<<dim3(56, 4), 256, 0, stream>>>(UpL, UpH, g2whh,
                                        w_pred, w_pred, w_pred,
                                        512, 512, 256, 256, 4, 1792, w_psup);

  k_ua<<<dim3(13, B_), 512, 0, stream>>>(uaLb, uaHb, lowres, highres, w_psup,
                                         w_ufL, w_ufH, nuL, nuH, w_eL, w_eH);
  k_ctx<<<dim3(17, B_), 256, 0, stream>>>(w_eL, w_eH, lowres, highres, w_ctx);

  k_mv<<<dim3(32, 8), 256, 0, stream>>>(g2wih, Wc, nullptr,
                                        w_ctx, w_ctx, nullptr,
                                        768, 256, CTX_, LDC_, 8, 1024, w_ps2);
  k_final<<<B_, 256, 0, stream>>>(w_ps2, w_psup, w_pred, w_emb, Ws, Wo, g2bih, g2bhh, out);
}

// Round 6
// 233.259 us; speedup vs baseline: 1.3398x; 1.3398x over previous
//
#include <hip/hip_runtime.h>

typedef __bf16 bf16_t;
typedef __bf16 bf16x8 __attribute__((ext_vector_type(8)));
typedef float  f32x4  __attribute__((ext_vector_type(4)));

constexpr int B_   = 64;
constexpr int EMB_ = 256;
constexpr int H_   = 256;
constexpr int NP_  = 512;
constexpr int NC_  = 144;
constexpr int CL_  = 684;
constexpr int CH_  = 342;
constexpr int LL_  = 256;
constexpr int LH_  = 576;
constexpr int OF_  = 256;
constexpr int CTX_ = 1026;
constexpr int LDC_ = 1032;  // ctx row stride
constexpr int CPL_ = 704;   // CL padded to 11*64
constexpr int CPH_ = 384;   // CH padded to 6*64

// ---- workspace layout (float offsets) ----
constexpr size_t OFF_EMB  = 0;        // [64][256]
constexpr size_t OFF_PRED = 16384;    // [64][256]
constexpr size_t OFF_PS1  = 32768;    // [4][64][1536]  gi1|gh1
constexpr size_t OFF_PSUP = 425984;   // [4][64][1792]  upL|upH|gh2
constexpr size_t OFF_PS2  = 884736;   // [8][64][1024]  gi2|wc
constexpr size_t OFF_OFL  = 1409024;  // [256][256]
constexpr size_t OFF_OFH  = 1474560;  // [576][256]
constexpr size_t OFF_UFL  = 1622016;  // [512][256]
constexpr size_t OFF_UFH  = 1753088;  // [512][576]
constexpr size_t OFF_EL   = 2048000;  // [64][256]
constexpr size_t OFF_EH   = 2064384;  // [64][576]
constexpr size_t OFF_CTX  = 2101248;  // [64][1032]
constexpr size_t OFF_UAL  = 2167296;  // bf16[512][704]
constexpr size_t OFF_UAH  = 2347520;  // bf16[512][384]

__device__ __forceinline__ float sigm(float x) { return 1.f / (1.f + expf(-x)); }
__device__ __forceinline__ float ftanh(float x) {
  float e = __expf(2.f * x);
  return 1.f - 2.f * __builtin_amdgcn_rcpf(e + 1.f);
}

// ---------------- merged front: U_a->bf16 | embed | out_f ----------------
__global__ __launch_bounds__(256) void k_front(
    const float* __restrict__ UaL, const float* __restrict__ UaH,
    bf16_t* __restrict__ dL, bf16_t* __restrict__ dH,
    const int* __restrict__ x, const float* __restrict__ embedding,
    float* __restrict__ emb,
    const float* __restrict__ aL, const float* __restrict__ aH,
    const float* __restrict__ fwL, const float* __restrict__ fbL,
    const float* __restrict__ fwH, const float* __restrict__ fbH,
    float* __restrict__ ofL, float* __restrict__ ofH) {
  __shared__ float al[LH_];
  __shared__ int nz;
  int bid = blockIdx.x, t = threadIdx.x;
  if (bid < 2176) {  // prep
    int idx = bid * 256 + t;
    if (idx < NP_ * CPL_) {
      int r = idx / CPL_, k = idx - r * CPL_;
      float v = (k < CL_) ? UaL[r * CL_ + k] : 0.f;
      dL[idx] = (bf16_t)v;
    } else {
      int i2 = idx - NP_ * CPL_;
      int r = i2 / CPH_, k = i2 - r * CPH_;
      float v = (k < CH_) ? UaH[r * CH_ + k] : 0.f;
      dH[i2] = (bf16_t)v;
    }
    return;
  }
  if (bid < 2240) {  // embed
    int b = bid - 2176;
    emb[b * EMB_ + t] = embedding[(size_t)x[b] * EMB_ + t];
    return;
  }
  // out_f (zero-alpha fast path)
  int bo = bid - 2240;
  bool low = bo < 256;
  const float* alpha = low ? aL : aH;
  int L = low ? LL_ : LH_;
  const float* fw = low ? fwL : fwH;
  const float* fb = low ? fbL : fbH;
  float* of = low ? ofL : ofH;
  int row = (low ? bo : bo - 256) * 256 + t;
  if (t == 0) nz = 0;
  __syncthreads();
  int any = 0;
  for (int l = t; l < L; l += 256) { float v = alpha[l]; al[l] = v; any |= (v != 0.f); }
  if (any) atomicOr(&nz, 1);
  __syncthreads();
  float s = fb[row];
  if (nz) {
    const float4* w4 = (const float4*)(fw + (size_t)row * L);
    for (int k = 0; k < L / 4; ++k) {
      float4 a4 = w4[k];
      s += al[4*k]*a4.x + al[4*k+1]*a4.y + al[4*k+2]*a4.z + al[4*k+3]*a4.w;
    }
  }
  of[row] = s;
}

// ---------------- generic split-K batched matvec ----------------
__global__ __launch_bounds__(256) void k_mv(
    const float* __restrict__ W0, const float* __restrict__ W1, const float* __restrict__ W2,
    const float* __restrict__ X0, const float* __restrict__ X1, const float* __restrict__ X2,
    int n0, int n1, int K, int ldx, int SK, int Nt,
    float* __restrict__ O) {
  int j0 = blockIdx.x * 32;
  int s  = blockIdx.y;
  const float* W; const float* X; int jr;
  if (j0 < n0)           { W = W0; X = X0; jr = j0; }
  else if (j0 < n0 + n1) { W = W1; X = X1; jr = j0 - n0; }
  else                   { W = W2; X = X2; jr = j0 - n0 - n1; }
  int NCh = (K + 63) >> 6;
  int c0 = (s * NCh) / SK, c1 = ((s + 1) * NCh) / SK;
  __shared__ float sX[64][68];
  __shared__ float sW[32][68];
  int t = threadIdx.x;
  int jg = t >> 5, bg = t & 31;
  float acc[4][2];
  #pragma unroll
  for (int r = 0; r < 4; ++r) { acc[r][0] = 0.f; acc[r][1] = 0.f; }
  for (int c = c0; c < c1; ++c) {
    int kb = c << 6;
    #pragma unroll
    for (int i = 0; i < 16; ++i) {
      int idx = t + (i << 8);
      int row = idx >> 6, col = idx & 63, k = kb + col;
      sX[row][col] = (k < K) ? X[(size_t)row * ldx + k] : 0.f;
    }
    #pragma unroll
    for (int i = 0; i < 8; ++i) {
      int idx = t + (i << 8);
      int row = idx >> 6, col = idx & 63, k = kb + col;
      sW[row][col] = (k < K) ? W[(size_t)(jr + row) * K + k] : 0.f;
    }
    __syncthreads();
    #pragma unroll
    for (int kg = 0; kg < 16; ++kg) {
      float4 xa = *(const float4*)&sX[bg][kg * 4];
      float4 xb = *(const float4*)&sX[bg + 32][kg * 4];
      #pragma unroll
      for (int r = 0; r < 4; ++r) {
        float4 w4 = *(const float4*)&sW[jg * 4 + r][kg * 4];
        acc[r][0] += w4.x*xa.x + w4.y*xa.y + w4.z*xa.z + w4.w*xa.w;
        acc[r][1] += w4.x*xb.x + w4.y*xb.y + w4.z*xb.z + w4.w*xb.w;
      }
    }
    __syncthreads();
  }
  #pragma unroll
  for (int r = 0; r < 4; ++r) {
    int j = j0 + jg * 4 + r;
    O[((size_t)(s * 64) + bg) * Nt + j]      = acc[r][0];
    O[((size_t)(s * 64) + bg + 32) * Nt + j] = acc[r][1];
  }
}

// ---------------- GRU1 activation (combine 4 K-slices) ----------------
__global__ __launch_bounds__(256) void k_act1(const float* __restrict__ PS1,
                                              const float* __restrict__ hidden,
                                              float* __restrict__ pred) {
  int b = blockIdx.x, t = threadIdx.x;
  float gr = 0, gz = 0, gn = 0, hr = 0, hz = 0, hn = 0;
  #pragma unroll
  for (int s = 0; s < 4; ++s) {
    const float* row = PS1 + ((size_t)(s * 64) + b) * 1536;
    gr += row[t]; gz += row[256 + t]; gn += row[512 + t];
    hr += row[768 + t]; hz += row[1024 + t]; hn += row[1280 + t];
  }
  float hv = hidden[b * H_ + t];
  float r = sigm(gr + hr);
  float z = sigm(gz + hz);
  float n = tanhf(gn + r * hn);
  pred[b * H_ + t] = (1.f - z) * n + z * hv;
}

// ---------------- u_f[p,l] = sum_o U_f[p,o] * out_f[l,o] ----------------
__global__ __launch_bounds__(256) void k_uf(
    const float* __restrict__ UfL, const float* __restrict__ UfH,
    const float* __restrict__ ofL, const float* __restrict__ ofH,
    float* __restrict__ ufL, float* __restrict__ ufH) {
  int bid = blockIdx.x, t = threadIdx.x;
  bool low = bid < 64;
  const float* Uf = low ? UfL : UfH;
  const float* of = low ? ofL : ofH;
  float* uf = low ? ufL : ufH;
  int L = low ? LL_ : LH_;
  int p0 = (low ? bid : bid - 64) * 8;
  __shared__ float ufs[8][OF_];
  for (int i = t; i < 8 * OF_; i += 256) ufs[i >> 8][i & 255] = Uf[(size_t)(p0 + (i >> 8)) * OF_ + (i & 255)];
  __syncthreads();
  for (int l = t; l < L; l += 256) {
    const float4* o4 = (const float4*)(of + (size_t)l * OF_);
    float acc[8] = {0,0,0,0,0,0,0,0};
    for (int k = 0; k < OF_ / 4; ++k) {
      float4 v = o4[k];
      #pragma unroll
      for (int i = 0; i < 8; ++i)
        acc[i] += v.x*ufs[i][4*k] + v.y*ufs[i][4*k+1] + v.z*ufs[i][4*k+2] + v.w*ufs[i][4*k+3];
    }
    #pragma unroll
    for (int i = 0; i < 8; ++i) uf[(size_t)(p0 + i) * L + l] = acc[i];
  }
}

// ---------------- u_a GEMM: A-frags direct from L2, dbuf LDS B, 1 barrier/chunk ----
// grid (13, 64): bx<4 -> low l-tile bx; bx>=4 -> high l-tile bx-4
// __launch_bounds__(512, 2): 256-VGPR budget -> NO SPILL (the round-3/5 killer)
__global__ __launch_bounds__(512, 2) void k_ua(
    const bf16_t* __restrict__ uaL, const bf16_t* __restrict__ uaH,
    const float* __restrict__ lowres, const float* __restrict__ highres,
    const float* __restrict__ psup,
    const float* __restrict__ ufL, const float* __restrict__ ufH,
    const float* __restrict__ nuL, const float* __restrict__ nuH,
    float* __restrict__ eL, float* __restrict__ eH) {
  int bx = blockIdx.x, b = blockIdx.y;
  bool lo = bx < 4;
  int lt = lo ? bx : bx - 4;
  int C  = lo ? CL_ : CH_;
  int CP = lo ? CPL_ : CPH_;
  int L  = lo ? LL_ : LH_;
  int upoff = lo ? 0 : 512;
  const bf16_t* Uab = lo ? uaL : uaH;
  const float* a    = lo ? lowres : highres;
  const float* uf   = lo ? ufL : ufH;
  const float* nu   = lo ? nuL : nuH;
  float* e_out      = lo ? eL : eH;
  int KC = CP >> 6;
  int l0 = lt * 64;
  int t = threadIdx.x;
  int w = t >> 6, lane = t & 63, g = lane >> 4, ln = lane & 15;

  __shared__ bf16_t Bsm[2][64 * 64];   // [buf][l][k-slot], slot ^= (l&7)
  __shared__ float ered[8][64];

  f32x4 acc[4][4];
  #pragma unroll
  for (int i = 0; i < 4; ++i)
    #pragma unroll
    for (int j = 0; j < 4; ++j) acc[i][j] = (f32x4){0.f, 0.f, 0.f, 0.f};

  const float* abase = a + ((size_t)b * C) * L + l0;
  int o = t >> 6, lcol = t & 63;                       // B staging coords
  const bf16_t* Abase = Uab + (size_t)(w * 64 + ln) * CP + g * 8;

  float bpre[8];
  bf16x8 af[2][4];

  // ---- prologue: chunk 0 ----
  {
    int cb = o * 8;
    #pragma unroll
    for (int j = 0; j < 8; ++j) {
      int c = cb + j;
      bpre[j] = (c < C) ? abase[(size_t)c * L + lcol] : 0.f;
    }
    #pragma unroll
    for (int ks = 0; ks < 2; ++ks)
      #pragma unroll
      for (int ps = 0; ps < 4; ++ps)
        af[ks][ps] = *(const bf16x8*)(Abase + (size_t)ps * 16 * CP + ks * 32);
    bf16x8 bv;
    #pragma unroll
    for (int j = 0; j < 8; ++j) bv[j] = (bf16_t)bpre[j];
    *(bf16x8*)&Bsm[0][lcol * 64 + ((o ^ (lcol & 7)) << 3)] = bv;
  }

  for (int kc = 0; kc < KC; ++kc) {
    __syncthreads();                       // B(kc) in buf[kc&1] visible
    int cur = kc & 1;
    bool more = (kc + 1 < KC);
    if (more) {                            // prefetch B(kc+1) into regs
      int cb = (kc + 1) * 64 + o * 8;
      #pragma unroll
      for (int j = 0; j < 8; ++j) {
        int c = cb + j;
        bpre[j] = (c < C) ? abase[(size_t)c * L + lcol] : 0.f;
      }
    }
    #pragma unroll
    for (int ks = 0; ks < 2; ++ks) {
      bf16x8 bfv[4];
      #pragma unroll
      for (int ts = 0; ts < 4; ++ts) {
        int lrow = ts * 16 + ln;
        int slot = ks * 4 + g;
        bfv[ts] = *(bf16x8*)&Bsm[cur][lrow * 64 + (((slot ^ (lrow & 7))) << 3)];
      }
      #pragma unroll
      for (int ts = 0; ts < 4; ++ts)
        #pragma unroll
        for (int ps = 0; ps < 4; ++ps)
          acc[ps][ts] = __builtin_amdgcn_mfma_f32_16x16x32_bf16(af[ks][ps], bfv[ts], acc[ps][ts], 0, 0, 0);
    }
    if (more) {                            // prefetch A-frags(kc+1) after last use
      #pragma unroll
      for (int ks = 0; ks < 2; ++ks)
        #pragma unroll
        for (int ps = 0; ps < 4; ++ps)
          af[ks][ps] = *(const bf16x8*)(Abase + (size_t)ps * 16 * CP + (kc + 1) * 64 + ks * 32);
      // write B(kc+1) into the other buffer (safe: its readers synced at loop top)
      bf16x8 bv;
      #pragma unroll
      for (int j = 0; j < 8; ++j) bv[j] = (bf16_t)bpre[j];
      *(bf16x8*)&Bsm[cur ^ 1][lcol * 64 + ((o ^ (lcol & 7)) << 3)] = bv;
    }
  }

  // epilogue: e_part = sum_p nu[p] * tanh(acc + up[b,p] + uf[p,l])
  float ep[4] = {0.f, 0.f, 0.f, 0.f};
  #pragma unroll
  for (int ps = 0; ps < 4; ++ps) {
    int pbase = w * 64 + ps * 16 + 4 * g;
    float upv[4], nuv[4];
    #pragma unroll
    for (int r = 0; r < 4; ++r) {
      float u = 0.f;
      #pragma unroll
      for (int s = 0; s < 4; ++s)
        u += psup[((size_t)(s * 64) + b) * 1792 + upoff + pbase + r];
      upv[r] = u; nuv[r] = nu[pbase + r];
    }
    #pragma unroll
    for (int ts = 0; ts < 4; ++ts) {
      int l = l0 + ts * 16 + ln;
      #pragma unroll
      for (int r = 0; r < 4; ++r) {
        float v = acc[ps][ts][r] + upv[r] + uf[(size_t)(pbase + r) * L + l];
        ep[ts] += nuv[r] * ftanh(v);
      }
    }
  }
  #pragma unroll
  for (int ts = 0; ts < 4; ++ts) {
    float v = ep[ts];
    v += __shfl_xor(v, 16, 64);
    v += __shfl_xor(v, 32, 64);
    if (lane < 16) ered[w][ts * 16 + ln] = v;
  }
  __syncthreads();
  if (t < 64) {
    float s = 0.f;
    #pragma unroll
    for (int ww = 0; ww < 8; ++ww) s += ered[ww][t];
    e_out[b * L + l0 + t] = s;
  }
}

// ---------------- fused softmax(e) + ctx tile  (grid 17 x 64) ----------------
__global__ __launch_bounds__(256) void k_ctx(
    const float* __restrict__ eL, const float* __restrict__ eH,
    const float* __restrict__ lowres, const float* __restrict__ highres,
    float* __restrict__ ctx) {
  int tile = blockIdx.x, b = blockIdx.y, t = threadIdx.x;
  bool low = tile < 11;
  int C = low ? CL_ : CH_;
  int L = low ? LL_ : LH_;
  int c0 = (low ? tile : tile - 11) * 64;
  const float* e = low ? eL + b * LL_ : eH + b * LH_;
  const float* a = (low ? lowres : highres) + ((size_t)b * C) * L;
  float* co = ctx + (size_t)b * LDC_ + (low ? 0 : CL_) + c0;
  int rows = min(64, C - c0);
  __shared__ float als[LH_];
  __shared__ float red4[4];
  __shared__ float red[64][4];
  int wid = t >> 6, lane = t & 63;
  float m = -3.4e38f;
  for (int l = t; l < L; l += 256) m = fmaxf(m, e[l]);
  #pragma unroll
  for (int s = 1; s < 64; s <<= 1) m = fmaxf(m, __shfl_xor(m, s, 64));
  if (lane == 0) red4[wid] = m;
  __syncthreads();
  m = fmaxf(fmaxf(red4[0], red4[1]), fmaxf(red4[2], red4[3]));
  __syncthreads();
  float sum = 0.f;
  for (int l = t; l < L; l += 256) { float v = __expf(e[l] - m); als[l] = v; sum += v; }
  #pragma unroll
  for (int s = 1; s < 64; s <<= 1) sum += __shfl_xor(sum, s, 64);
  if (lane == 0) red4[wid] = sum;
  __syncthreads();
  float inv = 1.f / (red4[0] + red4[1] + red4[2] + red4[3]);
  for (int l = t; l < L; l += 256) als[l] *= inv;
  __syncthreads();
  int r = t >> 2, q = t & 3;
  int Lq = L >> 2;
  float s = 0.f;
  if (r < rows) {
    const float4* a4 = (const float4*)(a + (size_t)(c0 + r) * L + q * Lq);
    const float* alq = als + q * Lq;
    for (int k = 0; k < (Lq >> 2); ++k) {
      float4 v = a4[k];
      s += alq[4*k]*v.x + alq[4*k+1]*v.y + alq[4*k+2]*v.z + alq[4*k+3]*v.w;
    }
  }
  red[r][q] = s;
  __syncthreads();
  if (q == 0 && r < rows)
    co[r] = red[r][0] + red[r][1] + red[r][2] + red[r][3];
}

// ---------------- GRU2 act + w_s + sv + out projection ----------------
__global__ __launch_bounds__(256) void k_final(
    const float* __restrict__ PS2, const float* __restrict__ PSUP,
    const float* __restrict__ pred, const float* __restrict__ emb,
    const float* __restrict__ Ws, const float* __restrict__ Wo,
    const float* __restrict__ b_ih, const float* __restrict__ b_hh,
    float* __restrict__ out) {
  int b = blockIdx.x, t = threadIdx.x;
  __shared__ float nh[H_], sv[EMB_];
  float gr = b_ih[t], gz = b_ih[256 + t], gn = b_ih[512 + t];
  float wc_t = 0.f;
  #pragma unroll
  for (int s = 0; s < 8; ++s) {
    const float* row = PS2 + ((size_t)(s * 64) + b) * 1024;
    gr += row[t]; gz += row[256 + t]; gn += row[512 + t];
    wc_t += row[768 + t];
  }
  float hr = b_hh[t], hz = b_hh[256 + t], hn = b_hh[512 + t];
  #pragma unroll
  for (int s = 0; s < 4; ++s) {
    const float* row = PSUP + ((size_t)(s * 64) + b) * 1792;
    hr += row[1024 + t]; hz += row[1280 + t]; hn += row[1536 + t];
  }
  float hv = pred[b * H_ + t];
  float r = sigm(gr + hr);
  float z = sigm(gz + hz);
  float n = tanhf(gn + r * hn);
  float h = (1.f - z) * n + z * hv;
  nh[t] = h;
  out[NC_ * B_ + b * H_ + t] = h;
  __syncthreads();
  {
    const float4* ws4 = (const float4*)(Ws + (size_t)t * H_);
    float s1 = 0.f;
    for (int k = 0; k < H_ / 4; ++k) {
      float4 v = ws4[k];
      s1 += nh[4*k]*v.x + nh[4*k+1]*v.y + nh[4*k+2]*v.z + nh[4*k+3]*v.w;
    }
    sv[t] = emb[b * EMB_ + t] + s1 + wc_t;
  }
  __syncthreads();
  if (t < NC_) {
    const float4* wo4 = (const float4*)(Wo + (size_t)t * EMB_);
    float s = 0.f;
    for (int k = 0; k < EMB_ / 4; ++k) {
      float4 v = wo4[k];
      s += sv[4*k]*v.x + sv[4*k+1]*v.y + sv[4*k+2]*v.z + sv[4*k+3]*v.w;
    }
    out[b * NC_ + t] = s;
  }
}

extern "C" void kernel_launch(void* const* d_in, const int* in_sizes, int n_in,
                              void* d_out, int out_size, void* d_ws, size_t ws_size,
                              hipStream_t stream) {
  (void)in_sizes; (void)n_in; (void)out_size; (void)ws_size;
  const int*   x       = (const int*)  d_in[0];
  const float* hidden  = (const float*)d_in[1];
  const float* lowres  = (const float*)d_in[2];
  const float* highres = (const float*)d_in[3];
  const float* aLow    = (const float*)d_in[4];
  const float* aHigh   = (const float*)d_in[5];
  const float* embd    = (const float*)d_in[6];
  const float* g1wih   = (const float*)d_in[7];
  const float* g1whh   = (const float*)d_in[8];
  const float* g1bih   = (const float*)d_in[9];
  const float* g1bhh   = (const float*)d_in[10];
  const float* g2wih   = (const float*)d_in[11];
  const float* g2whh   = (const float*)d_in[12];
  const float* g2bih   = (const float*)d_in[13];
  const float* g2bhh   = (const float*)d_in[14];
  const float* fwL     = (const float*)d_in[15];
  const float* fbL     = (const float*)d_in[16];
  const float* UpL     = (const float*)d_in[17];
  const float* UaL     = (const float*)d_in[18];
  const float* UfL     = (const float*)d_in[19];
  const float* nuL     = (const float*)d_in[20];
  const float* fwH     = (const float*)d_in[21];
  const float* fbH     = (const float*)d_in[22];
  const float* UpH     = (const float*)d_in[23];
  const float* UaH     = (const float*)d_in[24];
  const float* UfH     = (const float*)d_in[25];
  const float* nuH     = (const float*)d_in[26];
  const float* Wo      = (const float*)d_in[27];
  const float* Ws      = (const float*)d_in[28];
  const float* Wc      = (const float*)d_in[29];

  float* ws  = (float*)d_ws;
  float* out = (float*)d_out;
  float* w_emb  = ws + OFF_EMB;
  float* w_pred = ws + OFF_PRED;
  float* w_ps1  = ws + OFF_PS1;
  float* w_psup = ws + OFF_PSUP;
  float* w_ps2  = ws + OFF_PS2;
  float* w_ofL  = ws + OFF_OFL;
  float* w_ofH  = ws + OFF_OFH;
  float* w_ufL  = ws + OFF_UFL;
  float* w_ufH  = ws + OFF_UFH;
  float* w_eL   = ws + OFF_EL;
  float* w_eH   = ws + OFF_EH;
  float* w_ctx  = ws + OFF_CTX;
  bf16_t* uaLb  = (bf16_t*)(ws + OFF_UAL);
  bf16_t* uaHb  = (bf16_t*)(ws + OFF_UAH);

  k_front<<<3072, 256, 0, stream>>>(UaL, UaH, uaLb, uaHb, x, embd, w_emb,
                                    aLow, aHigh, fwL, fbL, fwH, fbH, w_ofL, w_ofH);
  k_uf<<<128, 256, 0, stream>>>(UfL, UfH, w_ofL, w_ofH, w_ufL, w_ufH);

  k_mv<<<dim3(48, 4), 256, 0, stream>>>(g1wih, g1whh, nullptr,
                                        w_emb, hidden, nullptr,
                                        768, 768, 256, 256, 4, 1536, w_ps1);
  k_act1<<<B_, 256, 0, stream>>>(w_ps1, hidden, w_pred);
  k_mv<<<dim3(56, 4), 256, 0, stream>>>(UpL, UpH, g2whh,
                                        w_pred, w_pred, w_pred,
                                        512, 512, 256, 256, 4, 1792, w_psup);

  k_ua<<<dim3(13, B_), 512, 0, stream>>>(uaLb, uaHb, lowres, highres, w_psup,
                                         w_ufL, w_ufH, nuL, nuH, w_eL, w_eH);
  k_ctx<<<dim3(17, B_), 256, 0, stream>>>(w_eL, w_eH, lowres, highres, w_ctx);

  k_mv<<<dim3(32, 8), 256, 0, stream>>>(g2wih, Wc, nullptr,
                                        w_ctx, w_ctx, nullptr,
                                        768, 256, CTX_, LDC_, 8, 1024, w_ps2);
  k_final<<<B_, 256, 0, stream>>>(w_ps2, w_psup, w_pred, w_emb, Ws, Wo, g2bih, g2bhh, out);
}

// Round 7
// 208.496 us; speedup vs baseline: 1.4989x; 1.1188x over previous
//
#include <hip/hip_runtime.h>

typedef __bf16 bf16_t;
typedef __bf16 bf16x8 __attribute__((ext_vector_type(8)));
typedef float  f32x4  __attribute__((ext_vector_type(4)));

constexpr int B_   = 64;
constexpr int EMB_ = 256;
constexpr int H_   = 256;
constexpr int NP_  = 512;
constexpr int NC_  = 144;
constexpr int CL_  = 684;
constexpr int CH_  = 342;
constexpr int LL_  = 256;
constexpr int LH_  = 576;
constexpr int OF_  = 256;
constexpr int CTX_ = 1026;
constexpr int LDC_ = 1032;  // ctx row stride
constexpr int CPL_ = 704;   // CL padded to 11*64
constexpr int CPH_ = 384;   // CH padded to 6*64

// ---- workspace layout (float offsets) ----
constexpr size_t OFF_EMB  = 0;        // [64][256]
constexpr size_t OFF_PRED = 16384;    // [64][256]
constexpr size_t OFF_PS1  = 32768;    // [4][64][1536]  gi1|gh1
constexpr size_t OFF_PSUP = 425984;   // [4][64][1792]  upL|upH|gh2
constexpr size_t OFF_PS2  = 884736;   // [8][64][1024]  gi2|wc
constexpr size_t OFF_OFL  = 1409024;  // [256][256]
constexpr size_t OFF_OFH  = 1474560;  // [576][256]
constexpr size_t OFF_UFL  = 1622016;  // [512][256]
constexpr size_t OFF_UFH  = 1753088;  // [512][576]
constexpr size_t OFF_EL   = 2048000;  // [64][256]
constexpr size_t OFF_EH   = 2064384;  // [64][576]
constexpr size_t OFF_CTX  = 2101248;  // [64][1032]
constexpr size_t OFF_UAL  = 2167296;  // bf16[512][704]
constexpr size_t OFF_UAH  = 2347520;  // bf16[512][384]

__device__ __forceinline__ float sigm(float x) { return 1.f / (1.f + expf(-x)); }
__device__ __forceinline__ float ftanh(float x) {
  float e = __expf(2.f * x);
  return 1.f - 2.f * __builtin_amdgcn_rcpf(e + 1.f);
}

// ---------------- merged front: U_a->bf16 | embed | out_f ----------------
__global__ __launch_bounds__(256) void k_front(
    const float* __restrict__ UaL, const float* __restrict__ UaH,
    bf16_t* __restrict__ dL, bf16_t* __restrict__ dH,
    const int* __restrict__ x, const float* __restrict__ embedding,
    float* __restrict__ emb,
    const float* __restrict__ aL, const float* __restrict__ aH,
    const float* __restrict__ fwL, const float* __restrict__ fbL,
    const float* __restrict__ fwH, const float* __restrict__ fbH,
    float* __restrict__ ofL, float* __restrict__ ofH) {
  __shared__ float al[LH_];
  __shared__ int nz;
  int bid = blockIdx.x, t = threadIdx.x;
  if (bid < 2176) {  // prep
    int idx = bid * 256 + t;
    if (idx < NP_ * CPL_) {
      int r = idx / CPL_, k = idx - r * CPL_;
      float v = (k < CL_) ? UaL[r * CL_ + k] : 0.f;
      dL[idx] = (bf16_t)v;
    } else {
      int i2 = idx - NP_ * CPL_;
      int r = i2 / CPH_, k = i2 - r * CPH_;
      float v = (k < CH_) ? UaH[r * CH_ + k] : 0.f;
      dH[i2] = (bf16_t)v;
    }
    return;
  }
  if (bid < 2240) {  // embed
    int b = bid - 2176;
    emb[b * EMB_ + t] = embedding[(size_t)x[b] * EMB_ + t];
    return;
  }
  // out_f (zero-alpha fast path)
  int bo = bid - 2240;
  bool low = bo < 256;
  const float* alpha = low ? aL : aH;
  int L = low ? LL_ : LH_;
  const float* fw = low ? fwL : fwH;
  const float* fb = low ? fbL : fbH;
  float* of = low ? ofL : ofH;
  int row = (low ? bo : bo - 256) * 256 + t;
  if (t == 0) nz = 0;
  __syncthreads();
  int any = 0;
  for (int l = t; l < L; l += 256) { float v = alpha[l]; al[l] = v; any |= (v != 0.f); }
  if (any) atomicOr(&nz, 1);
  __syncthreads();
  float s = fb[row];
  if (nz) {
    const float4* w4 = (const float4*)(fw + (size_t)row * L);
    for (int k = 0; k < L / 4; ++k) {
      float4 a4 = w4[k];
      s += al[4*k]*a4.x + al[4*k+1]*a4.y + al[4*k+2]*a4.z + al[4*k+3]*a4.w;
    }
  }
  of[row] = s;
}

// ---------------- merged: u_f GEMM (blocks 0..127) | GRU1 matvec (blocks 128..319) ----
__global__ __launch_bounds__(256) void k_ufmv(
    const float* __restrict__ UfL, const float* __restrict__ UfH,
    const float* __restrict__ ofL, const float* __restrict__ ofH,
    float* __restrict__ ufL, float* __restrict__ ufH,
    const float* __restrict__ W0, const float* __restrict__ W1,
    const float* __restrict__ X0, const float* __restrict__ X1,
    float* __restrict__ O) {
  int bid = blockIdx.x, t = threadIdx.x;
  if (bid < 128) {
    // ---- u_f[p,l] = sum_o U_f[p,o] * out_f[l,o] ----
    bool low = bid < 64;
    const float* Uf = low ? UfL : UfH;
    const float* of = low ? ofL : ofH;
    float* uf = low ? ufL : ufH;
    int L = low ? LL_ : LH_;
    int p0 = (low ? bid : bid - 64) * 8;
    __shared__ float ufs[8][OF_];
    for (int i = t; i < 8 * OF_; i += 256) ufs[i >> 8][i & 255] = Uf[(size_t)(p0 + (i >> 8)) * OF_ + (i & 255)];
    __syncthreads();
    for (int l = t; l < L; l += 256) {
      const float4* o4 = (const float4*)(of + (size_t)l * OF_);
      float acc[8] = {0,0,0,0,0,0,0,0};
      for (int k = 0; k < OF_ / 4; ++k) {
        float4 v = o4[k];
        #pragma unroll
        for (int i = 0; i < 8; ++i)
          acc[i] += v.x*ufs[i][4*k] + v.y*ufs[i][4*k+1] + v.z*ufs[i][4*k+2] + v.w*ufs[i][4*k+3];
      }
      #pragma unroll
      for (int i = 0; i < 8; ++i) uf[(size_t)(p0 + i) * L + l] = acc[i];
    }
    return;
  }
  // ---- GRU1 split-K matvec: gi1|gh1, N=1536, K=256, SK=4 ----
  {
    int mb = bid - 128;
    int jb = mb % 48, s = mb / 48;
    int j0 = jb * 32;
    const float* W; const float* X; int jr;
    if (j0 < 768) { W = W0; X = X0; jr = j0; }
    else          { W = W1; X = X1; jr = j0 - 768; }
    int kb = s << 6;
    __shared__ float sX[64][68];
    __shared__ float sW[32][68];
    int jg = t >> 5, bg = t & 31;
    float acc[4][2];
    #pragma unroll
    for (int r = 0; r < 4; ++r) { acc[r][0] = 0.f; acc[r][1] = 0.f; }
    #pragma unroll
    for (int i = 0; i < 16; ++i) {
      int idx = t + (i << 8);
      int row = idx >> 6, col = idx & 63;
      sX[row][col] = X[(size_t)row * 256 + kb + col];
    }
    #pragma unroll
    for (int i = 0; i < 8; ++i) {
      int idx = t + (i << 8);
      int row = idx >> 6, col = idx & 63;
      sW[row][col] = W[(size_t)(jr + row) * 256 + kb + col];
    }
    __syncthreads();
    #pragma unroll
    for (int kg = 0; kg < 16; ++kg) {
      float4 xa = *(const float4*)&sX[bg][kg * 4];
      float4 xb = *(const float4*)&sX[bg + 32][kg * 4];
      #pragma unroll
      for (int r = 0; r < 4; ++r) {
        float4 w4 = *(const float4*)&sW[jg * 4 + r][kg * 4];
        acc[r][0] += w4.x*xa.x + w4.y*xa.y + w4.z*xa.z + w4.w*xa.w;
        acc[r][1] += w4.x*xb.x + w4.y*xb.y + w4.z*xb.z + w4.w*xb.w;
      }
    }
    #pragma unroll
    for (int r = 0; r < 4; ++r) {
      int j = j0 + jg * 4 + r;
      O[((size_t)(s * 64) + bg) * 1536 + j]      = acc[r][0];
      O[((size_t)(s * 64) + bg + 32) * 1536 + j] = acc[r][1];
    }
  }
}

// ---------------- generic split-K batched matvec ----------------
__global__ __launch_bounds__(256) void k_mv(
    const float* __restrict__ W0, const float* __restrict__ W1, const float* __restrict__ W2,
    const float* __restrict__ X0, const float* __restrict__ X1, const float* __restrict__ X2,
    int n0, int n1, int K, int ldx, int SK, int Nt,
    float* __restrict__ O) {
  int j0 = blockIdx.x * 32;
  int s  = blockIdx.y;
  const float* W; const float* X; int jr;
  if (j0 < n0)           { W = W0; X = X0; jr = j0; }
  else if (j0 < n0 + n1) { W = W1; X = X1; jr = j0 - n0; }
  else                   { W = W2; X = X2; jr = j0 - n0 - n1; }
  int NCh = (K + 63) >> 6;
  int c0 = (s * NCh) / SK, c1 = ((s + 1) * NCh) / SK;
  __shared__ float sX[64][68];
  __shared__ float sW[32][68];
  int t = threadIdx.x;
  int jg = t >> 5, bg = t & 31;
  float acc[4][2];
  #pragma unroll
  for (int r = 0; r < 4; ++r) { acc[r][0] = 0.f; acc[r][1] = 0.f; }
  for (int c = c0; c < c1; ++c) {
    int kb = c << 6;
    #pragma unroll
    for (int i = 0; i < 16; ++i) {
      int idx = t + (i << 8);
      int row = idx >> 6, col = idx & 63, k = kb + col;
      sX[row][col] = (k < K) ? X[(size_t)row * ldx + k] : 0.f;
    }
    #pragma unroll
    for (int i = 0; i < 8; ++i) {
      int idx = t + (i << 8);
      int row = idx >> 6, col = idx & 63, k = kb + col;
      sW[row][col] = (k < K) ? W[(size_t)(jr + row) * K + k] : 0.f;
    }
    __syncthreads();
    #pragma unroll
    for (int kg = 0; kg < 16; ++kg) {
      float4 xa = *(const float4*)&sX[bg][kg * 4];
      float4 xb = *(const float4*)&sX[bg + 32][kg * 4];
      #pragma unroll
      for (int r = 0; r < 4; ++r) {
        float4 w4 = *(const float4*)&sW[jg * 4 + r][kg * 4];
        acc[r][0] += w4.x*xa.x + w4.y*xa.y + w4.z*xa.z + w4.w*xa.w;
        acc[r][1] += w4.x*xb.x + w4.y*xb.y + w4.z*xb.z + w4.w*xb.w;
      }
    }
    __syncthreads();
  }
  #pragma unroll
  for (int r = 0; r < 4; ++r) {
    int j = j0 + jg * 4 + r;
    O[((size_t)(s * 64) + bg) * Nt + j]      = acc[r][0];
    O[((size_t)(s * 64) + bg + 32) * Nt + j] = acc[r][1];
  }
}

// ---------------- GRU1 activation (combine 4 K-slices) ----------------
__global__ __launch_bounds__(256) void k_act1(const float* __restrict__ PS1,
                                              const float* __restrict__ hidden,
                                              float* __restrict__ pred) {
  int b = blockIdx.x, t = threadIdx.x;
  float gr = 0, gz = 0, gn = 0, hr = 0, hz = 0, hn = 0;
  #pragma unroll
  for (int s = 0; s < 4; ++s) {
    const float* row = PS1 + ((size_t)(s * 64) + b) * 1536;
    gr += row[t]; gz += row[256 + t]; gn += row[512 + t];
    hr += row[768 + t]; hz += row[1024 + t]; hn += row[1280 + t];
  }
  float hv = hidden[b * H_ + t];
  float r = sigm(gr + hr);
  float z = sigm(gz + hz);
  float n = tanhf(gn + r * hn);
  pred[b * H_ + t] = (1.f - z) * n + z * hv;
}

// ---------------- u_a GEMM: A-frags direct from L2, dbuf LDS B, 1 barrier/chunk ----
// grid (13, 64). __launch_bounds__(512, 2): 256-VGPR budget -> NO SPILL.
__global__ __launch_bounds__(512, 2) void k_ua(
    const bf16_t* __restrict__ uaL, const bf16_t* __restrict__ uaH,
    const float* __restrict__ lowres, const float* __restrict__ highres,
    const float* __restrict__ psup,
    const float* __restrict__ ufL, const float* __restrict__ ufH,
    const float* __restrict__ nuL, const float* __restrict__ nuH,
    float* __restrict__ eL, float* __restrict__ eH) {
  int bx = blockIdx.x, b = blockIdx.y;
  bool lo = bx < 4;
  int lt = lo ? bx : bx - 4;
  int C  = lo ? CL_ : CH_;
  int CP = lo ? CPL_ : CPH_;
  int L  = lo ? LL_ : LH_;
  int upoff = lo ? 0 : 512;
  const bf16_t* Uab = lo ? uaL : uaH;
  const float* a    = lo ? lowres : highres;
  const float* uf   = lo ? ufL : ufH;
  const float* nu   = lo ? nuL : nuH;
  float* e_out      = lo ? eL : eH;
  int KC = CP >> 6;
  int l0 = lt * 64;
  int t = threadIdx.x;
  int w = t >> 6, lane = t & 63, g = lane >> 4, ln = lane & 15;

  __shared__ bf16_t Bsm[2][64 * 64];   // [buf][l][k-slot], slot ^= (l&7)
  __shared__ float ered[8][64];

  f32x4 acc[4][4];
  #pragma unroll
  for (int i = 0; i < 4; ++i)
    #pragma unroll
    for (int j = 0; j < 4; ++j) acc[i][j] = (f32x4){0.f, 0.f, 0.f, 0.f};

  const float* abase = a + ((size_t)b * C) * L + l0;
  int o = t >> 6, lcol = t & 63;                       // B staging coords
  const bf16_t* Abase = Uab + (size_t)(w * 64 + ln) * CP + g * 8;

  float bpre[8];
  bf16x8 af[2][4];

  // ---- prologue: chunk 0 ----
  {
    int cb = o * 8;
    #pragma unroll
    for (int j = 0; j < 8; ++j) {
      int c = cb + j;
      bpre[j] = (c < C) ? abase[(size_t)c * L + lcol] : 0.f;
    }
    #pragma unroll
    for (int ks = 0; ks < 2; ++ks)
      #pragma unroll
      for (int ps = 0; ps < 4; ++ps)
        af[ks][ps] = *(const bf16x8*)(Abase + (size_t)ps * 16 * CP + ks * 32);
    bf16x8 bv;
    #pragma unroll
    for (int j = 0; j < 8; ++j) bv[j] = (bf16_t)bpre[j];
    *(bf16x8*)&Bsm[0][lcol * 64 + ((o ^ (lcol & 7)) << 3)] = bv;
  }

  for (int kc = 0; kc < KC; ++kc) {
    __syncthreads();                       // B(kc) in buf[kc&1] visible
    int cur = kc & 1;
    bool more = (kc + 1 < KC);
    if (more) {                            // prefetch B(kc+1) into regs
      int cb = (kc + 1) * 64 + o * 8;
      #pragma unroll
      for (int j = 0; j < 8; ++j) {
        int c = cb + j;
        bpre[j] = (c < C) ? abase[(size_t)c * L + lcol] : 0.f;
      }
    }
    #pragma unroll
    for (int ks = 0; ks < 2; ++ks) {
      bf16x8 bfv[4];
      #pragma unroll
      for (int ts = 0; ts < 4; ++ts) {
        int lrow = ts * 16 + ln;
        int slot = ks * 4 + g;
        bfv[ts] = *(bf16x8*)&Bsm[cur][lrow * 64 + (((slot ^ (lrow & 7))) << 3)];
      }
      #pragma unroll
      for (int ts = 0; ts < 4; ++ts)
        #pragma unroll
        for (int ps = 0; ps < 4; ++ps)
          acc[ps][ts] = __builtin_amdgcn_mfma_f32_16x16x32_bf16(af[ks][ps], bfv[ts], acc[ps][ts], 0, 0, 0);
    }
    if (more) {                            // prefetch A-frags(kc+1) after last use
      #pragma unroll
      for (int ks = 0; ks < 2; ++ks)
        #pragma unroll
        for (int ps = 0; ps < 4; ++ps)
          af[ks][ps] = *(const bf16x8*)(Abase + (size_t)ps * 16 * CP + (kc + 1) * 64 + ks * 32);
      bf16x8 bv;
      #pragma unroll
      for (int j = 0; j < 8; ++j) bv[j] = (bf16_t)bpre[j];
      *(bf16x8*)&Bsm[cur ^ 1][lcol * 64 + ((o ^ (lcol & 7)) << 3)] = bv;
    }
  }

  // epilogue: e_part = sum_p nu[p] * tanh(acc + up[b,p] + uf[p,l])
  float ep[4] = {0.f, 0.f, 0.f, 0.f};
  #pragma unroll
  for (int ps = 0; ps < 4; ++ps) {
    int pbase = w * 64 + ps * 16 + 4 * g;
    float upv[4], nuv[4];
    #pragma unroll
    for (int r = 0; r < 4; ++r) {
      float u = 0.f;
      #pragma unroll
      for (int s = 0; s < 4; ++s)
        u += psup[((size_t)(s * 64) + b) * 1792 + upoff + pbase + r];
      upv[r] = u; nuv[r] = nu[pbase + r];
    }
    #pragma unroll
    for (int ts = 0; ts < 4; ++ts) {
      int l = l0 + ts * 16 + ln;
      #pragma unroll
      for (int r = 0; r < 4; ++r) {
        float v = acc[ps][ts][r] + upv[r] + uf[(size_t)(pbase + r) * L + l];
        ep[ts] += nuv[r] * ftanh(v);
      }
    }
  }
  #pragma unroll
  for (int ts = 0; ts < 4; ++ts) {
    float v = ep[ts];
    v += __shfl_xor(v, 16, 64);
    v += __shfl_xor(v, 32, 64);
    if (lane < 16) ered[w][ts * 16 + ln] = v;
  }
  __syncthreads();
  if (t < 64) {
    float s = 0.f;
    #pragma unroll
    for (int ww = 0; ww < 8; ++ww) s += ered[ww][t];
    e_out[b * L + l0 + t] = s;
  }
}

// ---------------- fused softmax(e) + ctx tile  (grid 17 x 64) ----------------
__global__ __launch_bounds__(256) void k_ctx(
    const float* __restrict__ eL, const float* __restrict__ eH,
    const float* __restrict__ lowres, const float* __restrict__ highres,
    float* __restrict__ ctx) {
  int tile = blockIdx.x, b = blockIdx.y, t = threadIdx.x;
  bool low = tile < 11;
  int C = low ? CL_ : CH_;
  int L = low ? LL_ : LH_;
  int c0 = (low ? tile : tile - 11) * 64;
  const float* e = low ? eL + b * LL_ : eH + b * LH_;
  const float* a = (low ? lowres : highres) + ((size_t)b * C) * L;
  float* co = ctx + (size_t)b * LDC_ + (low ? 0 : CL_) + c0;
  int rows = min(64, C - c0);
  __shared__ float als[LH_];
  __shared__ float red4[4];
  __shared__ float red[64][4];
  int wid = t >> 6, lane = t & 63;
  float m = -3.4e38f;
  for (int l = t; l < L; l += 256) m = fmaxf(m, e[l]);
  #pragma unroll
  for (int s = 1; s < 64; s <<= 1) m = fmaxf(m, __shfl_xor(m, s, 64));
  if (lane == 0) red4[wid] = m;
  __syncthreads();
  m = fmaxf(fmaxf(red4[0], red4[1]), fmaxf(red4[2], red4[3]));
  __syncthreads();
  float sum = 0.f;
  for (int l = t; l < L; l += 256) { float v = __expf(e[l] - m); als[l] = v; sum += v; }
  #pragma unroll
  for (int s = 1; s < 64; s <<= 1) sum += __shfl_xor(sum, s, 64);
  if (lane == 0) red4[wid] = sum;
  __syncthreads();
  float inv = 1.f / (red4[0] + red4[1] + red4[2] + red4[3]);
  for (int l = t; l < L; l += 256) als[l] *= inv;
  __syncthreads();
  int r = t >> 2, q = t & 3;
  int Lq = L >> 2;
  float s = 0.f;
  if (r < rows) {
    const float4* a4 = (const float4*)(a + (size_t)(c0 + r) * L + q * Lq);
    const float* alq = als + q * Lq;
    for (int k = 0; k < (Lq >> 2); ++k) {
      float4 v = a4[k];
      s += alq[4*k]*v.x + alq[4*k+1]*v.y + alq[4*k+2]*v.z + alq[4*k+3]*v.w;
    }
  }
  red[r][q] = s;
  __syncthreads();
  if (q == 0 && r < rows)
    co[r] = red[r][0] + red[r][1] + red[r][2] + red[r][3];
}

// ---------------- GRU2 act + w_s + sv + out projection ----------------
__global__ __launch_bounds__(256) void k_final(
    const float* __restrict__ PS2, const float* __restrict__ PSUP,
    const float* __restrict__ pred, const float* __restrict__ emb,
    const float* __restrict__ Ws, const float* __restrict__ Wo,
    const float* __restrict__ b_ih, const float* __restrict__ b_hh,
    float* __restrict__ out) {
  int b = blockIdx.x, t = threadIdx.x;
  __shared__ float nh[H_], sv[EMB_];
  float gr = b_ih[t], gz = b_ih[256 + t], gn = b_ih[512 + t];
  float wc_t = 0.f;
  #pragma unroll
  for (int s = 0; s < 8; ++s) {
    const float* row = PS2 + ((size_t)(s * 64) + b) * 1024;
    gr += row[t]; gz += row[256 + t]; gn += row[512 + t];
    wc_t += row[768 + t];
  }
  float hr = b_hh[t], hz = b_hh[256 + t], hn = b_hh[512 + t];
  #pragma unroll
  for (int s = 0; s < 4; ++s) {
    const float* row = PSUP + ((size_t)(s * 64) + b) * 1792;
    hr += row[1024 + t]; hz += row[1280 + t]; hn += row[1536 + t];
  }
  float hv = pred[b * H_ + t];
  float r = sigm(gr + hr);
  float z = sigm(gz + hz);
  float n = tanhf(gn + r * hn);
  float h = (1.f - z) * n + z * hv;
  nh[t] = h;
  out[NC_ * B_ + b * H_ + t] = h;
  __syncthreads();
  {
    const float4* ws4 = (const float4*)(Ws + (size_t)t * H_);
    float s1 = 0.f;
    for (int k = 0; k < H_ / 4; ++k) {
      float4 v = ws4[k];
      s1 += nh[4*k]*v.x + nh[4*k+1]*v.y + nh[4*k+2]*v.z + nh[4*k+3]*v.w;
    }
    sv[t] = emb[b * EMB_ + t] + s1 + wc_t;
  }
  __syncthreads();
  if (t < NC_) {
    const float4* wo4 = (const float4*)(Wo + (size_t)t * EMB_);
    float s = 0.f;
    for (int k = 0; k < EMB_ / 4; ++k) {
      float4 v = wo4[k];
      s += sv[4*k]*v.x + sv[4*k+1]*v.y + sv[4*k+2]*v.z + sv[4*k+3]*v.w;
    }
    out[b * NC_ + t] = s;
  }
}

extern "C" void kernel_launch(void* const* d_in, const int* in_sizes, int n_in,
                              void* d_out, int out_size, void* d_ws, size_t ws_size,
                              hipStream_t stream) {
  (void)in_sizes; (void)n_in; (void)out_size; (void)ws_size;
  const int*   x       = (const int*)  d_in[0];
  const float* hidden  = (const float*)d_in[1];
  const float* lowres  = (const float*)d_in[2];
  const float* highres = (const float*)d_in[3];
  const float* aLow    = (const float*)d_in[4];
  const float* aHigh   = (const float*)d_in[5];
  const float* embd    = (const float*)d_in[6];
  const float* g1wih   = (const float*)d_in[7];
  const float* g1whh   = (const float*)d_in[8];
  const float* g1bih   = (const float*)d_in[9];
  const float* g1bhh   = (const float*)d_in[10];
  const float* g2wih   = (const float*)d_in[11];
  const float* g2whh   = (const float*)d_in[12];
  const float* g2bih   = (const float*)d_in[13];
  const float* g2bhh   = (const float*)d_in[14];
  const float* fwL     = (const float*)d_in[15];
  const float* fbL     = (const float*)d_in[16];
  const float* UpL     = (const float*)d_in[17];
  const float* UaL     = (const float*)d_in[18];
  const float* UfL     = (const float*)d_in[19];
  const float* nuL     = (const float*)d_in[20];
  const float* fwH     = (const float*)d_in[21];
  const float* fbH     = (const float*)d_in[22];
  const float* UpH     = (const float*)d_in[23];
  const float* UaH     = (const float*)d_in[24];
  const float* UfH     = (const float*)d_in[25];
  const float* nuH     = (const float*)d_in[26];
  const float* Wo      = (const float*)d_in[27];
  const float* Ws      = (const float*)d_in[28];
  const float* Wc      = (const float*)d_in[29];

  float* ws  = (float*)d_ws;
  float* out = (float*)d_out;
  float* w_emb  = ws + OFF_EMB;
  float* w_pred = ws + OFF_PRED;
  float* w_ps1  = ws + OFF_PS1;
  float* w_psup = ws + OFF_PSUP;
  float* w_ps2  = ws + OFF_PS2;
  float* w_ofL  = ws + OFF_OFL;
  float* w_ofH  = ws + OFF_OFH;
  float* w_ufL  = ws + OFF_UFL;
  float* w_ufH  = ws + OFF_UFH;
  float* w_eL   = ws + OFF_EL;
  float* w_eH   = ws + OFF_EH;
  float* w_ctx  = ws + OFF_CTX;
  bf16_t* uaLb  = (bf16_t*)(ws + OFF_UAL);
  bf16_t* uaHb  = (bf16_t*)(ws + OFF_UAH);

  k_front<<<3072, 256, 0, stream>>>(UaL, UaH, uaLb, uaHb, x, embd, w_emb,
                                    aLow, aHigh, fwL, fbL, fwH, fbH, w_ofL, w_ofH);
  // u_f GEMM  ||  GRU1 gi1|gh1 matvec (both depend only on k_front)
  k_ufmv<<<320, 256, 0, stream>>>(UfL, UfH, w_ofL, w_ofH, w_ufL, w_ufH,
                                  g1wih, g1whh, w_emb, hidden, w_ps1);
  k_act1<<<B_, 256, 0, stream>>>(w_ps1, hidden, w_pred);
  k_mv<<<dim3(56, 4), 256, 0, stream>>>(UpL, UpH, g2whh,
                                        w_pred, w_pred, w_pred,
                                        512, 512, 256, 256, 4, 1792, w_psup);

  k_ua<<<dim3(13, B_), 512, 0, stream>>>(uaLb, uaHb, lowres, highres, w_psup,
                                         w_ufL, w_ufH, nuL, nuH, w_eL, w_eH);
  k_ctx<<<dim3(17, B_), 256, 0, stream>>>(w_eL, w_eH, lowres, highres, w_ctx);

  k_mv<<<dim3(32, 8), 256, 0, stream>>>(g2wih, Wc, nullptr,
                                        w_ctx, w_ctx, nullptr,
                                        768, 256, CTX_, LDC_, 8, 1024, w_ps2);
  k_final<<<B_, 256, 0, stream>>>(w_ps2, w_psup, w_pred, w_emb, Ws, Wo, g2bih, g2bhh, out);
}